// Round 12
// baseline (284.189 us; speedup 1.0000x reference)
//
#include <hip/hip_runtime.h>
#include <hip/hip_bf16.h>
#include <math.h>

typedef __bf16 bf16x8 __attribute__((ext_vector_type(8)));
typedef float f32x4 __attribute__((ext_vector_type(4)));
typedef unsigned short u16x8 __attribute__((ext_vector_type(8)));

#define DEV __device__ __forceinline__

DEV unsigned short f2bf(float f){ __hip_bfloat16 h=__float2bfloat16(f); unsigned short u; __builtin_memcpy(&u,&h,2); return u; }
DEV float bf2f(unsigned short u){ __hip_bfloat16 h; __builtin_memcpy(&h,&u,2); return __bfloat162float(h); }

// tanh-form GELU: exp is HW (v_exp_f32), rcp is HW.
DEV float gelu_f(float v){
  float u = v*(0.7978845608f + 0.0356774081f*v*v);
  float e = __expf(2.0f*u);
  float t = 1.0f - 2.0f*__builtin_amdgcn_rcpf(e + 1.0f);
  return 0.5f*v*(1.0f + t);
}

DEV void gl2lds16(const void* g, void* l){
  __builtin_amdgcn_global_load_lds((const __attribute__((address_space(1))) void*)g,
                                   (__attribute__((address_space(3))) void*)l, 16, 0, 0);
}

// ---- tiled weight transpose: WT[n][k] (bf16) = W[k][n] (f32), 64x64 tiles.
__global__ __launch_bounds__(256) void k_wtt(const float* __restrict__ w1a,
                                             const float* __restrict__ w1b,
                                             const float* __restrict__ w2a,
                                             const float* __restrict__ w2b,
                                             unsigned short* __restrict__ o1a,
                                             unsigned short* __restrict__ o1b,
                                             unsigned short* __restrict__ o2a,
                                             unsigned short* __restrict__ o2b){
  __shared__ float tl[64][65];
  int bid = blockIdx.x;
  const float* W; unsigned short* O; int NN, tile_id;
  if (bid < 16)      { W = w1a; O = o1a; NN = 256; tile_id = bid; }
  else if (bid < 32) { W = w1b; O = o1b; NN = 256; tile_id = bid - 16; }
  else if (bid < 96) { W = w2a; O = o2a; NN = 512; tile_id = bid - 32; }
  else               { W = w2b; O = o2b; NN = 512; tile_id = bid - 96; }
  int tpr = NN >> 6;
  int tr = tile_id / tpr, tc = tile_id % tpr;
  int tid = threadIdx.x;
  int r = tid >> 2, cseg = (tid & 3) << 4;
  #pragma unroll
  for (int j = 0; j < 4; ++j){
    float4 v = *(const float4*)(W + (size_t)(tr*64 + r)*NN + tc*64 + cseg + j*4);
    tl[r][cseg + j*4 + 0] = v.x;
    tl[r][cseg + j*4 + 1] = v.y;
    tl[r][cseg + j*4 + 2] = v.z;
    tl[r][cseg + j*4 + 3] = v.w;
  }
  __syncthreads();
  int rn = tid >> 2, kseg = (tid & 3) << 4;
  #pragma unroll
  for (int h = 0; h < 2; ++h){
    u16x8 o;
    #pragma unroll
    for (int j = 0; j < 8; ++j) o[j] = f2bf(tl[kseg + h*8 + j][rn]);
    *(u16x8*)(O + (size_t)(tc*64 + rn)*NN + tr*64 + kseg + h*8) = o;
  }
}

// ---- LN1 + transpose + bf16 x copy, DMA-staged:
// 512 threads, 32 p-rows per block. Phase 1: global_load_lds stages the whole
// 32x512 f32 block (64 KB) -> deep memory parallelism with no register deps
// (the mechanism the compiler can't defeat). Phase 2: waves LN rows from LDS,
// write xb coalesced, park mu/rs in LDS. Phase 3: one c-column per thread,
// scalar LDS reads (2 lanes/bank = free), normalize at write time, 64-B
// contiguous ht runs per thread.
// x[b][p][c] f32 -> ht[b][c][p] bf16 (layernormed), xb[b][p][c] bf16 (copy)
__global__ __launch_bounds__(512) void k_ln1x(const float* __restrict__ x,
                                              const float* __restrict__ g,
                                              const float* __restrict__ be,
                                              unsigned short* __restrict__ ht,
                                              unsigned short* __restrict__ xb){
  __shared__ float X[32*512];          // 64 KB
  __shared__ float mus[32], rss[32];
  int blk = blockIdx.x;
  int b = blk >> 3, p0 = (blk & 7) << 5;
  int tid = threadIdx.x, w = tid >> 6, l = tid & 63;
  const float* xbase = x + (((size_t)b << 8) + p0) * 512;
  // phase 1: DMA-stage 64 KB (4096 x 16 B; 8 per thread, no reg deps)
  #pragma unroll
  for (int i = 0; i < 8; ++i){
    int q = (i << 9) + tid;            // 0..4095
    gl2lds16(xbase + q*4, (char*)X + (size_t)q*16);
  }
  __syncthreads();
  // phase 2: per-row LN stats + xb copy (reads from LDS)
  #pragma unroll
  for (int i = 0; i < 4; ++i){
    int pl = (i << 3) + w;             // wave w owns rows w, w+8, w+16, w+24
    const float* row = X + pl*512 + l*8;
    float4 v0 = *(const float4*)row;
    float4 v1 = *(const float4*)(row + 4);
    u16x8 rc;
    rc[0]=f2bf(v0.x); rc[1]=f2bf(v0.y); rc[2]=f2bf(v0.z); rc[3]=f2bf(v0.w);
    rc[4]=f2bf(v1.x); rc[5]=f2bf(v1.y); rc[6]=f2bf(v1.z); rc[7]=f2bf(v1.w);
    *(u16x8*)(xb + (((size_t)b << 8) + p0 + pl)*512 + l*8) = rc;
    float s  = v0.x+v0.y+v0.z+v0.w + v1.x+v1.y+v1.z+v1.w;
    float s2 = v0.x*v0.x+v0.y*v0.y+v0.z*v0.z+v0.w*v0.w
             + v1.x*v1.x+v1.y*v1.y+v1.z*v1.z+v1.w*v1.w;
    #pragma unroll
    for (int off = 32; off; off >>= 1){ s += __shfl_xor(s, off); s2 += __shfl_xor(s2, off); }
    float mu = s * (1.0f/512.0f);
    float rs = rsqrtf(s2*(1.0f/512.0f) - mu*mu + 1e-6f);
    if (l == 0){ mus[pl] = mu; rss[pl] = rs; }
  }
  __syncthreads();
  // phase 3: transposed ht write, one c per thread (c = tid)
  int c = tid;
  float gc = g[c], bc = be[c];
  u16x8 o0, o1, o2, o3;
  #pragma unroll
  for (int p = 0; p < 8; ++p)  o0[p] = f2bf((X[p*512 + c]        - mus[p])     *rss[p]     *gc + bc);
  #pragma unroll
  for (int p = 0; p < 8; ++p)  o1[p] = f2bf((X[(p+8)*512 + c]    - mus[p+8])   *rss[p+8]   *gc + bc);
  #pragma unroll
  for (int p = 0; p < 8; ++p)  o2[p] = f2bf((X[(p+16)*512 + c]   - mus[p+16])  *rss[p+16]  *gc + bc);
  #pragma unroll
  for (int p = 0; p < 8; ++p)  o3[p] = f2bf((X[(p+24)*512 + c]   - mus[p+24])  *rss[p+24]  *gc + bc);
  unsigned short* dst = ht + ((size_t)b << 17) + (size_t)c*256 + p0;
  *(u16x8*)(dst)      = o0;
  *(u16x8*)(dst + 8)  = o1;
  *(u16x8*)(dst + 16) = o2;
  *(u16x8*)(dst + 24) = o3;
}

// ---- streaming residual + LN2, one row per wave:
// h2[r][c] = LN( t[r][c] + xb[r][c] ),  r = (b,p)
__global__ __launch_bounds__(256) void k_tl2s(const unsigned short* __restrict__ t,
                                              const unsigned short* __restrict__ xb,
                                              const float* __restrict__ g,
                                              const float* __restrict__ be,
                                              unsigned short* __restrict__ h2){
  int tid = threadIdx.x, w = tid >> 6, l = tid & 63;
  float4 gv0 = *(const float4*)(g  + l*8);
  float4 gv1 = *(const float4*)(g  + l*8 + 4);
  float4 bv0 = *(const float4*)(be + l*8);
  float4 bv1 = *(const float4*)(be + l*8 + 4);
  int r = blockIdx.x*4 + w;                     // 65536 waves, 1 row each
  size_t off = (size_t)r*512 + l*8;
  u16x8 tv = *(const u16x8*)(t + off);
  u16x8 xv = *(const u16x8*)(xb + off);
  float v[8];
  #pragma unroll
  for (int j = 0; j < 8; ++j) v[j] = bf2f(tv[j]) + bf2f(xv[j]);
  float s = 0.f, s2 = 0.f;
  #pragma unroll
  for (int j = 0; j < 8; ++j){ s += v[j]; s2 += v[j]*v[j]; }
  #pragma unroll
  for (int o2i = 32; o2i; o2i >>= 1){ s += __shfl_xor(s, o2i); s2 += __shfl_xor(s2, o2i); }
  float mu = s * (1.0f/512.0f);
  float rs = rsqrtf(s2*(1.0f/512.0f) - mu*mu + 1e-6f);
  u16x8 o;
  o[0]=f2bf((v[0]-mu)*rs*gv0.x+bv0.x);
  o[1]=f2bf((v[1]-mu)*rs*gv0.y+bv0.y);
  o[2]=f2bf((v[2]-mu)*rs*gv0.z+bv0.z);
  o[3]=f2bf((v[3]-mu)*rs*gv0.w+bv0.w);
  o[4]=f2bf((v[4]-mu)*rs*gv1.x+bv1.x);
  o[5]=f2bf((v[5]-mu)*rs*gv1.y+bv1.y);
  o[6]=f2bf((v[6]-mu)*rs*gv1.z+bv1.z);
  o[7]=f2bf((v[7]-mu)*rs*gv1.w+bv1.w);
  *(u16x8*)(h2 + off) = o;
}

// ---- m97-style 128x128 GEMM, C[m][n] = epi(sum_k A[m][k]*BT[n][k] + bias[n])
// MODE 0: outb = bf16(gelu(v))   MODE 1: outb = bf16(v)
// MODE 2: outf = f32(v) + f32(res[m][n])
template<int N, int KT, int MODE>
__global__ __launch_bounds__(256, 2) void k_gemm(
    const unsigned short* __restrict__ A,
    const unsigned short* __restrict__ BT,
    const float* __restrict__ bias,
    unsigned short* __restrict__ outb,
    float* __restrict__ outf,
    const unsigned short* __restrict__ res)
{
  constexpr int K = KT*64;
  constexpr int nTn = N/128;
  constexpr int EPITCH = 176;
  constexpr int EREG   = 64*EPITCH;
  __shared__ char lds[4*EREG];
  char* lsA = lds;
  char* lsB = lds + 16384;

  int nwg = gridDim.x, bid = blockIdx.x;
  int wgid = ((nwg & 7) == 0) ? ((bid & 7)*(nwg >> 3) + (bid >> 3)) : bid;
  int tm = wgid / nTn, tn = wgid % nTn;
  size_t m0 = (size_t)tm * 128;
  int n0 = tn * 128;

  const int tid = threadIdx.x;
  const int w = tid >> 6, l = tid & 63;
  const int wm = w >> 1, wn = w & 1;
  const int la = l & 15, lg = l >> 4;

  f32x4 acc[4][4];
  #pragma unroll
  for (int i = 0; i < 4; ++i)
    #pragma unroll
    for (int j = 0; j < 4; ++j) acc[i][j] = (f32x4){0.f,0.f,0.f,0.f};

  for (int kt = 0; kt < KT; ++kt){
    int kb = kt << 6;
    #pragma unroll
    for (int i = 0; i < 4; ++i){
      int q = (i << 8) + tid;
      int row = q >> 3, sc = q & 7;
      int cc = sc ^ (row & 7);
      gl2lds16(A  + (m0 + row)*K + kb + (cc << 3), lsA + q*16);
      gl2lds16(BT + (size_t)(n0 + row)*K + kb + (cc << 3), lsB + q*16);
    }
    __syncthreads();
    #pragma unroll
    for (int ks = 0; ks < 2; ++ks){
      int c = (ks << 2) + lg;
      bf16x8 af[4], bfr[4];
      #pragma unroll
      for (int mi = 0; mi < 4; ++mi){
        int rr = (wm << 6) + (mi << 4) + la;
        af[mi] = *(const bf16x8*)(lsA + ((rr << 3) + (c ^ (rr & 7)))*16);
      }
      #pragma unroll
      for (int ni = 0; ni < 4; ++ni){
        int rn = (wn << 6) + (ni << 4) + la;
        bfr[ni] = *(const bf16x8*)(lsB + ((rn << 3) + (c ^ (rn & 7)))*16);
      }
      #pragma unroll
      for (int mi = 0; mi < 4; ++mi)
        #pragma unroll
        for (int ni = 0; ni < 4; ++ni)
          acc[mi][ni] = __builtin_amdgcn_mfma_f32_16x16x32_bf16(af[mi], bfr[ni], acc[mi][ni], 0, 0, 0);
    }
    __syncthreads();
  }

  char* ep = lds + w*EREG;
  #pragma unroll
  for (int ni = 0; ni < 4; ++ni){
    int colw = (ni << 4) + la;
    float bv = bias[n0 + (wn << 6) + colw];
    #pragma unroll
    for (int mi = 0; mi < 4; ++mi){
      #pragma unroll
      for (int rg = 0; rg < 4; ++rg){
        float v = acc[mi][ni][rg] + bv;
        if (MODE == 0) v = gelu_f(v);
        int r = (mi << 4) + (lg << 2) + rg;
        *(unsigned short*)(ep + r*EPITCH + colw*2) = f2bf(v);
      }
    }
  }
  __syncthreads();

  #pragma unroll
  for (int i = 0; i < 8; ++i){
    int q = (i << 8) + tid;
    int r = q >> 4, ck = q & 15;
    int wreg = ((r >> 6) << 1) | (ck >> 3);
    u16x8 val = *(const u16x8*)(lds + wreg*EREG + (r & 63)*EPITCH + (ck & 7)*16);
    size_t go = (m0 + r)*N + n0 + (ck << 3);
    if (MODE != 2){
      *(u16x8*)(outb + go) = val;
    } else {
      u16x8 rv = *(const u16x8*)(res + go);
      float4 o0, o1;
      o0.x = bf2f(val[0]) + bf2f(rv[0]);
      o0.y = bf2f(val[1]) + bf2f(rv[1]);
      o0.z = bf2f(val[2]) + bf2f(rv[2]);
      o0.w = bf2f(val[3]) + bf2f(rv[3]);
      o1.x = bf2f(val[4]) + bf2f(rv[4]);
      o1.y = bf2f(val[5]) + bf2f(rv[5]);
      o1.z = bf2f(val[6]) + bf2f(rv[6]);
      o1.w = bf2f(val[7]) + bf2f(rv[7]);
      *(float4*)(outf + go)     = o0;
      *(float4*)(outf + go + 4) = o1;
    }
  }
}

// ---- token G2, transposed-output: t_nat[b][p][c] = sum_k wt1b[p][k]*U[(b,c)][k] + b1b[p]
__global__ __launch_bounds__(256, 2) void k_gemmT(
    const unsigned short* __restrict__ A,
    const unsigned short* __restrict__ BT,
    const float* __restrict__ bias,
    unsigned short* __restrict__ outb)
{
  constexpr int K = 256, KT = 4;
  constexpr int EPITCH = 176;
  constexpr int EREG   = 64*EPITCH;
  __shared__ char lds[4*EREG];
  char* lsA = lds;
  char* lsB = lds + 16384;

  int nwg = gridDim.x, bid = blockIdx.x;
  int wgid = (bid & 7)*(nwg >> 3) + (bid >> 3);
  int tm = wgid & 1, tn = wgid >> 1;
  size_t m0 = (size_t)tm * 128;
  int n0 = tn * 128;
  int bb = n0 >> 9, c0 = n0 & 511;

  const int tid = threadIdx.x;
  const int w = tid >> 6, l = tid & 63;
  const int wm = w >> 1, wn = w & 1;
  const int la = l & 15, lg = l >> 4;

  f32x4 acc[4][4];
  #pragma unroll
  for (int i = 0; i < 4; ++i)
    #pragma unroll
    for (int j = 0; j < 4; ++j) acc[i][j] = (f32x4){0.f,0.f,0.f,0.f};

  for (int kt = 0; kt < KT; ++kt){
    int kb = kt << 6;
    #pragma unroll
    for (int i = 0; i < 4; ++i){
      int q = (i << 8) + tid;
      int row = q >> 3, sc = q & 7;
      int cc = sc ^ (row & 7);
      gl2lds16(A  + (m0 + row)*K + kb + (cc << 3), lsA + q*16);
      gl2lds16(BT + (size_t)(n0 + row)*K + kb + (cc << 3), lsB + q*16);
    }
    __syncthreads();
    #pragma unroll
    for (int ks = 0; ks < 2; ++ks){
      int c = (ks << 2) + lg;
      bf16x8 af[4], bfr[4];
      #pragma unroll
      for (int mi = 0; mi < 4; ++mi){
        int rr = (wm << 6) + (mi << 4) + la;
        af[mi] = *(const bf16x8*)(lsA + ((rr << 3) + (c ^ (rr & 7)))*16);
      }
      #pragma unroll
      for (int ni = 0; ni < 4; ++ni){
        int rn = (wn << 6) + (ni << 4) + la;
        bfr[ni] = *(const bf16x8*)(lsB + ((rn << 3) + (c ^ (rn & 7)))*16);
      }
      #pragma unroll
      for (int mi = 0; mi < 4; ++mi)
        #pragma unroll
        for (int ni = 0; ni < 4; ++ni)
          acc[mi][ni] = __builtin_amdgcn_mfma_f32_16x16x32_bf16(af[mi], bfr[ni], acc[mi][ni], 0, 0, 0);
    }
    __syncthreads();
  }

  char* ep = lds + w*EREG;
  #pragma unroll
  for (int mi = 0; mi < 4; ++mi){
    int rb = (mi << 4) + (lg << 2);
    float4 bq = *(const float4*)(bias + m0 + (wm << 6) + rb);
    #pragma unroll
    for (int ni = 0; ni < 4; ++ni){
      int colw = (ni << 4) + la;
      #pragma unroll
      for (int rg = 0; rg < 4; ++rg){
        float v = acc[mi][ni][rg] + ((const float*)&bq)[rg];
        *(unsigned short*)(ep + (rb + rg)*EPITCH + colw*2) = f2bf(v);
      }
    }
  }
  __syncthreads();

  #pragma unroll
  for (int i = 0; i < 8; ++i){
    int q = (i << 8) + tid;
    int r = q >> 4, ck = q & 15;
    int wreg = ((r >> 6) << 1) | (ck >> 3);
    u16x8 val = *(const u16x8*)(lds + wreg*EREG + (r & 63)*EPITCH + (ck & 7)*16);
    size_t go = ((size_t)bb << 17) + (m0 + r)*512 + c0 + (ck << 3);
    *(u16x8*)(outb + go) = val;
  }
}

extern "C" void kernel_launch(void* const* d_in, const int* in_sizes, int n_in,
                              void* d_out, int out_size, void* d_ws, size_t ws_size,
                              hipStream_t stream) {
  const float* x   = (const float*)d_in[0];
  const float* lng = (const float*)d_in[1];
  const float* lnb = (const float*)d_in[2];
  const float* w1a = (const float*)d_in[3];
  const float* b1a = (const float*)d_in[4];
  const float* w1b = (const float*)d_in[5];
  const float* b1b = (const float*)d_in[6];
  const float* w2a = (const float*)d_in[7];
  const float* b2a = (const float*)d_in[8];
  const float* w2b = (const float*)d_in[9];
  const float* b2b = (const float*)d_in[10];
  float* out = (float*)d_out;
  char* ws = (char*)d_ws;
  unsigned short* bufA = (unsigned short*)ws;                         // 64 MiB
  unsigned short* bufB = (unsigned short*)(ws + (size_t)(64u << 20)); // 64 MiB
  unsigned short* wt1a = (unsigned short*)(ws + (size_t)(128u << 20));
  unsigned short* wt1b = wt1a + 256*256;
  unsigned short* wt2a = wt1b + 256*256;
  unsigned short* wt2b = wt2a + 512*512;
  unsigned short* xb   = (unsigned short*)d_out;  // scratch in d_out (consumed
                                                  // by k_tl2s before final write)

  k_wtt<<<160, 256, 0, stream>>>(w1a, w1b, w2a, w2b, wt1a, wt1b, wt2a, wt2b);

  // token mixing
  k_ln1x<<<2048, 512, 0, stream>>>(x, lng, lnb, bufA, xb);                          // ht, xb
  k_gemm<256, 4, 0><<<2048, 256, 0, stream>>>(bufA, wt1a, b1a, bufB, nullptr, nullptr); // U
  k_gemmT<<<2048, 256, 0, stream>>>(wt1b, bufB, b1b, bufA);                         // t_nat [b][p][c]

  // residual + LN2 (one row per wave)
  k_tl2s<<<16384, 256, 0, stream>>>(bufA, xb, lng, lnb, bufB);                      // h2

  // channel mixing
  k_gemm<512, 8, 0><<<2048, 256, 0, stream>>>(bufB, wt2a, b2a, bufA, nullptr, nullptr); // u2
  k_gemm<512, 8, 2><<<2048, 256, 0, stream>>>(bufA, wt2b, b2b, nullptr, out, bufB); // out
}

// Round 13
// 269.717 us; speedup vs baseline: 1.0537x; 1.0537x over previous
//
#include <hip/hip_runtime.h>
#include <hip/hip_bf16.h>
#include <math.h>

typedef __bf16 bf16x8 __attribute__((ext_vector_type(8)));
typedef float f32x4 __attribute__((ext_vector_type(4)));
typedef unsigned short u16x8 __attribute__((ext_vector_type(8)));

#define DEV __device__ __forceinline__

DEV unsigned short f2bf(float f){ __hip_bfloat16 h=__float2bfloat16(f); unsigned short u; __builtin_memcpy(&u,&h,2); return u; }
DEV float bf2f(unsigned short u){ __hip_bfloat16 h; __builtin_memcpy(&h,&u,2); return __bfloat162float(h); }

// tanh-form GELU: exp is HW (v_exp_f32), rcp is HW.
DEV float gelu_f(float v){
  float u = v*(0.7978845608f + 0.0356774081f*v*v);
  float e = __expf(2.0f*u);
  float t = 1.0f - 2.0f*__builtin_amdgcn_rcpf(e + 1.0f);
  return 0.5f*v*(1.0f + t);
}

DEV void gl2lds16(const void* g, void* l){
  __builtin_amdgcn_global_load_lds((const __attribute__((address_space(1))) void*)g,
                                   (__attribute__((address_space(3))) void*)l, 16, 0, 0);
}

// ---- tiled weight transpose: WT[n][k] (bf16) = W[k][n] (f32), 64x64 tiles.
__global__ __launch_bounds__(256) void k_wtt(const float* __restrict__ w1a,
                                             const float* __restrict__ w1b,
                                             const float* __restrict__ w2a,
                                             const float* __restrict__ w2b,
                                             unsigned short* __restrict__ o1a,
                                             unsigned short* __restrict__ o1b,
                                             unsigned short* __restrict__ o2a,
                                             unsigned short* __restrict__ o2b){
  __shared__ float tl[64][65];
  int bid = blockIdx.x;
  const float* W; unsigned short* O; int NN, tile_id;
  if (bid < 16)      { W = w1a; O = o1a; NN = 256; tile_id = bid; }
  else if (bid < 32) { W = w1b; O = o1b; NN = 256; tile_id = bid - 16; }
  else if (bid < 96) { W = w2a; O = o2a; NN = 512; tile_id = bid - 32; }
  else               { W = w2b; O = o2b; NN = 512; tile_id = bid - 96; }
  int tpr = NN >> 6;
  int tr = tile_id / tpr, tc = tile_id % tpr;
  int tid = threadIdx.x;
  int r = tid >> 2, cseg = (tid & 3) << 4;
  #pragma unroll
  for (int j = 0; j < 4; ++j){
    float4 v = *(const float4*)(W + (size_t)(tr*64 + r)*NN + tc*64 + cseg + j*4);
    tl[r][cseg + j*4 + 0] = v.x;
    tl[r][cseg + j*4 + 1] = v.y;
    tl[r][cseg + j*4 + 2] = v.z;
    tl[r][cseg + j*4 + 3] = v.w;
  }
  __syncthreads();
  int rn = tid >> 2, kseg = (tid & 3) << 4;
  #pragma unroll
  for (int h = 0; h < 2; ++h){
    u16x8 o;
    #pragma unroll
    for (int j = 0; j < 8; ++j) o[j] = f2bf(tl[kseg + h*8 + j][rn]);
    *(u16x8*)(O + (size_t)(tc*64 + rn)*NN + tr*64 + kseg + h*8) = o;
  }
}

// ---- LN1 + transpose + bf16 x copy (round-11 proven form):
// x[b][p][c] f32 -> ht[b][c][p] bf16 (layernormed), xb[b][p][c] bf16 (copy)
__global__ __launch_bounds__(512) void k_ln1x(const float* __restrict__ x,
                                              const float* __restrict__ g,
                                              const float* __restrict__ be,
                                              unsigned short* __restrict__ ht,
                                              unsigned short* __restrict__ xb){
  __shared__ unsigned short tile[32][512];
  int blk = blockIdx.x;
  int b = blk >> 3, p0 = (blk & 7) << 5;
  int tid = threadIdx.x, w = tid >> 6, l = tid & 63;
  float4 gv0 = *(const float4*)(g  + l*8);
  float4 gv1 = *(const float4*)(g  + l*8 + 4);
  float4 bv0 = *(const float4*)(be + l*8);
  float4 bv1 = *(const float4*)(be + l*8 + 4);
  const float* xbase = x + (((size_t)b << 8) + p0) * 512;
  #pragma unroll
  for (int i = 0; i < 4; ++i){
    int pl = (i << 3) + w;
    const float* row = xbase + (size_t)pl*512 + l*8;
    float4 v0 = *(const float4*)row;
    float4 v1 = *(const float4*)(row + 4);
    u16x8 rc;
    rc[0]=f2bf(v0.x); rc[1]=f2bf(v0.y); rc[2]=f2bf(v0.z); rc[3]=f2bf(v0.w);
    rc[4]=f2bf(v1.x); rc[5]=f2bf(v1.y); rc[6]=f2bf(v1.z); rc[7]=f2bf(v1.w);
    *(u16x8*)(xb + (((size_t)b << 8) + p0 + pl)*512 + l*8) = rc;
    float s  = v0.x+v0.y+v0.z+v0.w + v1.x+v1.y+v1.z+v1.w;
    float s2 = v0.x*v0.x+v0.y*v0.y+v0.z*v0.z+v0.w*v0.w
             + v1.x*v1.x+v1.y*v1.y+v1.z*v1.z+v1.w*v1.w;
    #pragma unroll
    for (int off = 32; off; off >>= 1){ s += __shfl_xor(s, off); s2 += __shfl_xor(s2, off); }
    float mu = s * (1.0f/512.0f);
    float rs = rsqrtf(s2*(1.0f/512.0f) - mu*mu + 1e-6f);
    u16x8 o;
    o[0]=f2bf((v0.x-mu)*rs*gv0.x+bv0.x);
    o[1]=f2bf((v0.y-mu)*rs*gv0.y+bv0.y);
    o[2]=f2bf((v0.z-mu)*rs*gv0.z+bv0.z);
    o[3]=f2bf((v0.w-mu)*rs*gv0.w+bv0.w);
    o[4]=f2bf((v1.x-mu)*rs*gv1.x+bv1.x);
    o[5]=f2bf((v1.y-mu)*rs*gv1.y+bv1.y);
    o[6]=f2bf((v1.z-mu)*rs*gv1.z+bv1.z);
    o[7]=f2bf((v1.w-mu)*rs*gv1.w+bv1.w);
    *(u16x8*)(&tile[pl][(l ^ ((pl >> 3) << 1)) << 3]) = o;   // swizzled chunk
  }
  __syncthreads();
  unsigned short* hb = ht + ((size_t)b << 17);   // b * 512 * 256
  #pragma unroll
  for (int it = 0; it < 4; ++it){
    int c = (it << 7) + (tid >> 2);
    int q = tid & 3, pch = q << 3;
    int cs = c ^ (q << 4);
    u16x8 o;
    #pragma unroll
    for (int j = 0; j < 8; ++j) o[j] = tile[pch + j][cs];
    *(u16x8*)(hb + (size_t)c*256 + p0 + pch) = o;
  }
}

// ---- streaming residual + LN2, one row per wave:
__global__ __launch_bounds__(256) void k_tl2s(const unsigned short* __restrict__ t,
                                              const unsigned short* __restrict__ xb,
                                              const float* __restrict__ g,
                                              const float* __restrict__ be,
                                              unsigned short* __restrict__ h2){
  int tid = threadIdx.x, w = tid >> 6, l = tid & 63;
  float4 gv0 = *(const float4*)(g  + l*8);
  float4 gv1 = *(const float4*)(g  + l*8 + 4);
  float4 bv0 = *(const float4*)(be + l*8);
  float4 bv1 = *(const float4*)(be + l*8 + 4);
  int r = blockIdx.x*4 + w;
  size_t off = (size_t)r*512 + l*8;
  u16x8 tv = *(const u16x8*)(t + off);
  u16x8 xv = *(const u16x8*)(xb + off);
  float v[8];
  #pragma unroll
  for (int j = 0; j < 8; ++j) v[j] = bf2f(tv[j]) + bf2f(xv[j]);
  float s = 0.f, s2 = 0.f;
  #pragma unroll
  for (int j = 0; j < 8; ++j){ s += v[j]; s2 += v[j]*v[j]; }
  #pragma unroll
  for (int o2i = 32; o2i; o2i >>= 1){ s += __shfl_xor(s, o2i); s2 += __shfl_xor(s2, o2i); }
  float mu = s * (1.0f/512.0f);
  float rs = rsqrtf(s2*(1.0f/512.0f) - mu*mu + 1e-6f);
  u16x8 o;
  o[0]=f2bf((v[0]-mu)*rs*gv0.x+bv0.x);
  o[1]=f2bf((v[1]-mu)*rs*gv0.y+bv0.y);
  o[2]=f2bf((v[2]-mu)*rs*gv0.z+bv0.z);
  o[3]=f2bf((v[3]-mu)*rs*gv0.w+bv0.w);
  o[4]=f2bf((v[4]-mu)*rs*gv1.x+bv1.x);
  o[5]=f2bf((v[5]-mu)*rs*gv1.y+bv1.y);
  o[6]=f2bf((v[6]-mu)*rs*gv1.z+bv1.z);
  o[7]=f2bf((v[7]-mu)*rs*gv1.w+bv1.w);
  *(u16x8*)(h2 + off) = o;
}

// ---- fused token MLP:
// t[b][p][c] = b1b[p] + sum_p1 wt1b[p][p1] * gelu(b1a[p1] + sum_p' ht[bc][p']*wt1a[p1][p'])
// Block: 64 bc-rows, full p1=256 (stage 1), full p=256 (stage 2), 256 thr.
// U (64x256 bf16) lives in LDS between stages; output written in natural layout.
__global__ __launch_bounds__(256, 2) void k_tok(
    const unsigned short* __restrict__ ht,    // [131072][256]
    const unsigned short* __restrict__ w1aT,  // [p1][p'] 256x256
    const unsigned short* __restrict__ w1bT,  // [p][p1]  256x256
    const float* __restrict__ b1a,
    const float* __restrict__ b1b,
    unsigned short* __restrict__ t)           // [256][256][512]
{
  constexpr int EPITCH = 144;                 // 16B-aligned epilogue pitch
  __shared__ char lsA[8192];                  // stage1 A: 64 rows x 128B
  __shared__ char lsW[EPITCH*256];            // 36KB: stage1 B / stage2 A / epilogue
  __shared__ char Ul[32768];                  // U: 64 x 256 bf16, chunk-swizzled

  int nwg = gridDim.x, bid = blockIdx.x;
  int wgid = (bid & 7)*(nwg >> 3) + (bid >> 3);   // grid 2048, %8==0
  size_t bc0 = (size_t)wgid * 64;
  int b = (int)(bc0 >> 9), c0 = (int)(bc0 & 511);

  const int tid = threadIdx.x;
  const int w = tid >> 6, l = tid & 63;
  const int la = l & 15, lg = l >> 4;

  f32x4 acc[4][4];
  #pragma unroll
  for (int i = 0; i < 4; ++i)
    #pragma unroll
    for (int j = 0; j < 4; ++j) acc[i][j] = (f32x4){0.f,0.f,0.f,0.f};

  // ===== stage 1: U = gelu(ht-tile @ w1a + b1a)   (m=64 bc, n=256 p1, k=256)
  for (int kt = 0; kt < 4; ++kt){
    int kb = kt << 6;
    #pragma unroll
    for (int i = 0; i < 2; ++i){
      int q = (i << 8) + tid;
      int row = q >> 3, sc = q & 7, cc = sc ^ (row & 7);
      gl2lds16(ht + (bc0 + row)*256 + kb + (cc << 3), lsA + q*16);
    }
    #pragma unroll
    for (int i = 0; i < 8; ++i){
      int q = (i << 8) + tid;
      int row = q >> 3, sc = q & 7, cc = sc ^ (row & 7);
      gl2lds16(w1aT + (size_t)row*256 + kb + (cc << 3), lsW + q*16);
    }
    __syncthreads();
    #pragma unroll
    for (int ks = 0; ks < 2; ++ks){
      int c = (ks << 2) + lg;
      bf16x8 af[4], bfr[4];
      #pragma unroll
      for (int mi = 0; mi < 4; ++mi){
        int rr = (mi << 4) + la;                       // bc-row (all waves share)
        af[mi] = *(const bf16x8*)(lsA + ((rr << 3) + (c ^ (rr & 7)))*16);
      }
      #pragma unroll
      for (int ni = 0; ni < 4; ++ni){
        int rn = (w << 6) + (ni << 4) + la;            // p1-row, wave n-split
        bfr[ni] = *(const bf16x8*)(lsW + ((rn << 3) + (c ^ (rn & 7)))*16);
      }
      #pragma unroll
      for (int mi = 0; mi < 4; ++mi)
        #pragma unroll
        for (int ni = 0; ni < 4; ++ni)
          acc[mi][ni] = __builtin_amdgcn_mfma_f32_16x16x32_bf16(af[mi], bfr[ni], acc[mi][ni], 0, 0, 0);
    }
    __syncthreads();
  }
  // U-write: bias(p1) + gelu, chunk-swizzled rows of 512B (32 chunks)
  #pragma unroll
  for (int ni = 0; ni < 4; ++ni){
    int p1 = (w << 6) + (ni << 4) + la;
    float bv = b1a[p1];
    int ckW = p1 >> 3, cw = p1 & 7;
    #pragma unroll
    for (int mi = 0; mi < 4; ++mi){
      #pragma unroll
      for (int rg = 0; rg < 4; ++rg){
        int bcr = (mi << 4) + (lg << 2) + rg;
        float v = gelu_f(acc[mi][ni][rg] + bv);
        *(unsigned short*)(Ul + (size_t)bcr*512 + (((ckW ^ (bcr & 7)) << 4) + (cw << 1))) = f2bf(v);
        acc[mi][ni][rg] = 0.0f;
      }
    }
  }
  __syncthreads();

  // ===== stage 2: t-tile = wt1b @ U^T + b1b   (m=256 p, n=64 bc, k=256 p1)
  for (int kt2 = 0; kt2 < 4; ++kt2){
    int kb = kt2 << 6;
    #pragma unroll
    for (int i = 0; i < 8; ++i){
      int q = (i << 8) + tid;
      int row = q >> 3, sc = q & 7, cc = sc ^ (row & 7);
      gl2lds16(w1bT + (size_t)row*256 + kb + (cc << 3), lsW + q*16);
    }
    __syncthreads();
    #pragma unroll
    for (int ks = 0; ks < 2; ++ks){
      int cch = (ks << 2) + lg;                        // chunk within kt2
      int cki = (kt2 << 3) + cch;                      // global chunk 0..31
      bf16x8 af[4], bfr[4];
      #pragma unroll
      for (int mi = 0; mi < 4; ++mi){
        int rp = (w << 6) + (mi << 4) + la;            // p-row, wave m-split
        af[mi] = *(const bf16x8*)(lsW + ((rp << 3) + (cch ^ (rp & 7)))*16);
      }
      #pragma unroll
      for (int ni = 0; ni < 4; ++ni){
        int rbc = (ni << 4) + la;                      // bc-row 0..63
        bfr[ni] = *(const bf16x8*)(Ul + (((size_t)rbc << 5) + (cki ^ (rbc & 7)))*16);
      }
      #pragma unroll
      for (int mi = 0; mi < 4; ++mi)
        #pragma unroll
        for (int ni = 0; ni < 4; ++ni)
          acc[mi][ni] = __builtin_amdgcn_mfma_f32_16x16x32_bf16(af[mi], bfr[ni], acc[mi][ni], 0, 0, 0);
    }
    __syncthreads();
  }

  // ===== epilogue: bias(p) per-row, stage via lsW (pitch 144), coalesced store
  #pragma unroll
  for (int mi = 0; mi < 4; ++mi){
    int rb = (w << 6) + (mi << 4) + (lg << 2);
    float4 bq = *(const float4*)(b1b + rb);
    #pragma unroll
    for (int ni = 0; ni < 4; ++ni){
      int col = (ni << 4) + la;
      #pragma unroll
      for (int rg = 0; rg < 4; ++rg){
        float v = acc[mi][ni][rg] + ((const float*)&bq)[rg];
        *(unsigned short*)(lsW + (rb + rg)*EPITCH + col*2) = f2bf(v);
      }
    }
  }
  __syncthreads();
  #pragma unroll
  for (int i = 0; i < 8; ++i){
    int q = (i << 8) + tid;
    int r = q >> 3, ck = q & 7;
    u16x8 val = *(const u16x8*)(lsW + r*EPITCH + ck*16);
    *(u16x8*)(t + ((size_t)b << 17) + (size_t)r*512 + c0 + (ck << 3)) = val;
  }
}

// ---- m97-style 128x128 GEMM (channel mixing), C[m][n] = epi(A·BT^T + bias)
// MODE 0: outb = bf16(gelu(v))   MODE 2: outf = f32(v) + f32(res[m][n])
template<int N, int KT, int MODE>
__global__ __launch_bounds__(256, 2) void k_gemm(
    const unsigned short* __restrict__ A,
    const unsigned short* __restrict__ BT,
    const float* __restrict__ bias,
    unsigned short* __restrict__ outb,
    float* __restrict__ outf,
    const unsigned short* __restrict__ res)
{
  constexpr int K = KT*64;
  constexpr int nTn = N/128;
  constexpr int EPITCH = 176;
  constexpr int EREG   = 64*EPITCH;
  __shared__ char lds[4*EREG];
  char* lsA = lds;
  char* lsB = lds + 16384;

  int nwg = gridDim.x, bid = blockIdx.x;
  int wgid = ((nwg & 7) == 0) ? ((bid & 7)*(nwg >> 3) + (bid >> 3)) : bid;
  int tm = wgid / nTn, tn = wgid % nTn;
  size_t m0 = (size_t)tm * 128;
  int n0 = tn * 128;

  const int tid = threadIdx.x;
  const int w = tid >> 6, l = tid & 63;
  const int wm = w >> 1, wn = w & 1;
  const int la = l & 15, lg = l >> 4;

  f32x4 acc[4][4];
  #pragma unroll
  for (int i = 0; i < 4; ++i)
    #pragma unroll
    for (int j = 0; j < 4; ++j) acc[i][j] = (f32x4){0.f,0.f,0.f,0.f};

  for (int kt = 0; kt < KT; ++kt){
    int kb = kt << 6;
    #pragma unroll
    for (int i = 0; i < 4; ++i){
      int q = (i << 8) + tid;
      int row = q >> 3, sc = q & 7;
      int cc = sc ^ (row & 7);
      gl2lds16(A  + (m0 + row)*K + kb + (cc << 3), lsA + q*16);
      gl2lds16(BT + (size_t)(n0 + row)*K + kb + (cc << 3), lsB + q*16);
    }
    __syncthreads();
    #pragma unroll
    for (int ks = 0; ks < 2; ++ks){
      int c = (ks << 2) + lg;
      bf16x8 af[4], bfr[4];
      #pragma unroll
      for (int mi = 0; mi < 4; ++mi){
        int rr = (wm << 6) + (mi << 4) + la;
        af[mi] = *(const bf16x8*)(lsA + ((rr << 3) + (c ^ (rr & 7)))*16);
      }
      #pragma unroll
      for (int ni = 0; ni < 4; ++ni){
        int rn = (wn << 6) + (ni << 4) + la;
        bfr[ni] = *(const bf16x8*)(lsB + ((rn << 3) + (c ^ (rn & 7)))*16);
      }
      #pragma unroll
      for (int mi = 0; mi < 4; ++mi)
        #pragma unroll
        for (int ni = 0; ni < 4; ++ni)
          acc[mi][ni] = __builtin_amdgcn_mfma_f32_16x16x32_bf16(af[mi], bfr[ni], acc[mi][ni], 0, 0, 0);
    }
    __syncthreads();
  }

  char* ep = lds + w*EREG;
  #pragma unroll
  for (int ni = 0; ni < 4; ++ni){
    int colw = (ni << 4) + la;
    float bv = bias[n0 + (wn << 6) + colw];
    #pragma unroll
    for (int mi = 0; mi < 4; ++mi){
      #pragma unroll
      for (int rg = 0; rg < 4; ++rg){
        float v = acc[mi][ni][rg] + bv;
        if (MODE == 0) v = gelu_f(v);
        int r = (mi << 4) + (lg << 2) + rg;
        *(unsigned short*)(ep + r*EPITCH + colw*2) = f2bf(v);
      }
    }
  }
  __syncthreads();

  #pragma unroll
  for (int i = 0; i < 8; ++i){
    int q = (i << 8) + tid;
    int r = q >> 4, ck = q & 15;
    int wreg = ((r >> 6) << 1) | (ck >> 3);
    u16x8 val = *(const u16x8*)(lds + wreg*EREG + (r & 63)*EPITCH + (ck & 7)*16);
    size_t go = (m0 + r)*N + n0 + (ck << 3);
    if (MODE != 2){
      *(u16x8*)(outb + go) = val;
    } else {
      u16x8 rv = *(const u16x8*)(res + go);
      float4 o0, o1;
      o0.x = bf2f(val[0]) + bf2f(rv[0]);
      o0.y = bf2f(val[1]) + bf2f(rv[1]);
      o0.z = bf2f(val[2]) + bf2f(rv[2]);
      o0.w = bf2f(val[3]) + bf2f(rv[3]);
      o1.x = bf2f(val[4]) + bf2f(rv[4]);
      o1.y = bf2f(val[5]) + bf2f(rv[5]);
      o1.z = bf2f(val[6]) + bf2f(rv[6]);
      o1.w = bf2f(val[7]) + bf2f(rv[7]);
      *(float4*)(outf + go)     = o0;
      *(float4*)(outf + go + 4) = o1;
    }
  }
}

extern "C" void kernel_launch(void* const* d_in, const int* in_sizes, int n_in,
                              void* d_out, int out_size, void* d_ws, size_t ws_size,
                              hipStream_t stream) {
  const float* x   = (const float*)d_in[0];
  const float* lng = (const float*)d_in[1];
  const float* lnb = (const float*)d_in[2];
  const float* w1a = (const float*)d_in[3];
  const float* b1a = (const float*)d_in[4];
  const float* w1b = (const float*)d_in[5];
  const float* b1b = (const float*)d_in[6];
  const float* w2a = (const float*)d_in[7];
  const float* b2a = (const float*)d_in[8];
  const float* w2b = (const float*)d_in[9];
  const float* b2b = (const float*)d_in[10];
  float* out = (float*)d_out;
  char* ws = (char*)d_ws;
  unsigned short* bufA = (unsigned short*)ws;                         // 64 MiB
  unsigned short* bufB = (unsigned short*)(ws + (size_t)(64u << 20)); // 64 MiB
  unsigned short* wt1a = (unsigned short*)(ws + (size_t)(128u << 20));
  unsigned short* wt1b = wt1a + 256*256;
  unsigned short* wt2a = wt1b + 256*256;
  unsigned short* wt2b = wt2a + 512*512;
  unsigned short* xb   = (unsigned short*)d_out;  // scratch in d_out (consumed
                                                  // by k_tl2s before final write)

  k_wtt<<<160, 256, 0, stream>>>(w1a, w1b, w2a, w2b, wt1a, wt1b, wt2a, wt2b);

  // token mixing: LN1+transpose, then fused (gelu GEMM + GEMM) pair
  k_ln1x<<<2048, 512, 0, stream>>>(x, lng, lnb, bufA, xb);                  // ht, xb
  k_tok<<<2048, 256, 0, stream>>>(bufA, wt1a, wt1b, b1a, b1b, bufB);        // t_nat [b][p][c]

  // residual + LN2
  k_tl2s<<<16384, 256, 0, stream>>>(bufB, xb, lng, lnb, bufA);              // h2

  // channel mixing
  k_gemm<512, 8, 0><<<2048, 256, 0, stream>>>(bufA, wt2a, b2a, bufB, nullptr, nullptr); // u2
  k_gemm<512, 8, 2><<<2048, 256, 0, stream>>>(bufB, wt2b, b2b, nullptr, out, bufA);     // out
}